// Round 9
// baseline (201.657 us; speedup 1.0000x reference)
//
#include <hip/hip_runtime.h>
#include <stdint.h>

#define NG   64      // graphs
#define N0   1024    // nodes layer 1
#define N1   512     // nodes layer 2 (k1)
#define K2   256     // k at layer 2
#define DD   128     // feature dim
#define NE   16384   // edges per graph
#define NOUT 64      // output dim

__device__ __forceinline__ float waveReduceSum(float v) {
    for (int off = 32; off > 0; off >>= 1) v += __shfl_xor(v, off, 64);
    return v;
}

// Hybrid bitonic sort, descending, 1 thread = 1 element.
// j<64 passes via shfl (no barriers), j>=64 via LDS (2 barriers each).
template<int NN>
__device__ __forceinline__ unsigned long long bitonic_desc(
    unsigned long long key, unsigned long long* lds, int i)
{
    for (int k2 = 2; k2 <= NN; k2 <<= 1) {
        for (int j = k2 >> 1; j > 0; j >>= 1) {
            unsigned long long p;
            if (j >= 64) {
                __syncthreads();
                lds[i] = key;
                __syncthreads();
                p = lds[i ^ j];
            } else {
                p = __shfl_xor(key, j, 64);
            }
            bool keepMax = (((i & k2) == 0) == ((i & j) == 0));
            if (keepMax ? (p > key) : (p < key)) key = p;
        }
    }
    return key;
}

// key = (monotone u32 of score) << 32 | (nn-1-i): descending sort gives
// score desc, index asc on ties — exact jax.lax.top_k semantics.
// All real keys have mapped-u > 0, so a 0-key pad sinks below every real key.
__device__ __forceinline__ unsigned long long make_key(float attnv, float sgn, int i, int nn) {
    float sc = tanhf(attnv * sgn);
    unsigned int u = __float_as_uint(sc);
    u = (u & 0x80000000u) ? ~u : (u | 0x80000000u);
    return ((unsigned long long)u << 32) | (unsigned int)(nn - 1 - i);
}

// ---------------------------------------------------------------------------
// ONE kernel: block g = full 2-layer SAGPool + readout for graph g.
// 1024 threads (16 waves). All intermediates live in LDS (~36 KB).
// ---------------------------------------------------------------------------
__global__ __launch_bounds__(1024) void sag_all_kernel(
    const float* __restrict__ x0,     // (G, N0, D)
    const int*   __restrict__ ei,     // (G, 2, NE)
    const float* __restrict__ w_rel,  // (2, D)
    const float* __restrict__ b_rel,  // (2,)
    const float* __restrict__ w_root, // (2, D)
    const float* __restrict__ w_sel,  // (2,)
    const float* __restrict__ W_lin,  // (2D, OUT)
    const float* __restrict__ b_lin,  // (OUT,)
    float* __restrict__ out)          // (G, OUT)
{
    __shared__ float srel[N0];
    __shared__ float attn[N0];
    __shared__ unsigned long long keys[N0];
    __shared__ int   nidx[N0];
    __shared__ int   p1l[N1];
    __shared__ float t1l[N1];
    __shared__ float srel2[N1];
    __shared__ float attn2[N1];
    __shared__ int   cn0[K2];
    __shared__ float cs[K2];
    __shared__ float sm[4][DD], mm[4][DD], rr[2 * DD], po[4][NOUT];

    const int g = blockIdx.x, i = threadIdx.x;
    const int wave = i >> 6, lane = i & 63;
    const float* xg   = x0 + (size_t)g * N0 * DD;
    const int*   base = ei + (size_t)g * 2 * NE;

    // ---- Phase 0: layer-1 dots (same per-row arithmetic as R8 dots1) ----
    {
        float wr0 = w_rel[lane * 2],  wr1 = w_rel[lane * 2 + 1];
        float wo0 = w_root[lane * 2], wo1 = w_root[lane * 2 + 1];
        float brel = b_rel[0];
        #pragma unroll
        for (int it = 0; it < 16; ++it) {
            int rowBase = (it * 16 + wave) * 4;
            #pragma unroll
            for (int t = 0; t < 4; ++t) {
                int row = rowBase + t;
                const float2 v = *(const float2*)(xg + (size_t)row * DD + lane * 2);
                float pr  = waveReduceSum(v.x * wr0 + v.y * wr1);
                float po_ = waveReduceSum(v.x * wo0 + v.y * wo1);
                if (lane == 0) { srel[row] = pr; attn[row] = po_ + brel; }
            }
        }
    }
    __syncthreads();

    // ---- Phase 1: layer-1 edge scatter (LDS atomics) ----
    #pragma unroll
    for (int it = 0; it < 4; ++it) {
        int eo = (it * 1024 + i) * 4;
        const int4 s4 = *(const int4*)(base + eo);
        const int4 d4 = *(const int4*)(base + NE + eo);
        atomicAdd(&attn[d4.x], srel[s4.x]);
        atomicAdd(&attn[d4.y], srel[s4.y]);
        atomicAdd(&attn[d4.z], srel[s4.z]);
        atomicAdd(&attn[d4.w], srel[s4.w]);
    }
    __syncthreads();

    // ---- Phase 2: score + sort-1024 + select top-512 (all in LDS) ----
    {
        const float sgn = (w_sel[0] >= 0.f) ? 1.f : -1.f;
        unsigned long long key = make_key(attn[i], sgn, i, N0);
        key = bitonic_desc<N0>(key, keys, i);
        int idx = (N0 - 1) - (int)(key & 0xffffffffu);
        unsigned int ku = (unsigned int)(key >> 32);
        unsigned int fb = (ku & 0x80000000u) ? (ku ^ 0x80000000u) : ~ku;
        nidx[idx] = (i < N1) ? i : -1;          // unique idx per thread
        if (i < N1) { p1l[i] = idx; t1l[i] = __uint_as_float(fb); }
    }
    __syncthreads();

    // ---- Phase 3: layer-2 dots through p1l (same arithmetic as gdots2) ----
    {
        float wr0 = w_rel[DD + lane * 2],  wr1 = w_rel[DD + lane * 2 + 1];
        float wo0 = w_root[DD + lane * 2], wo1 = w_root[DD + lane * 2 + 1];
        float brel = b_rel[1];
        #pragma unroll
        for (int it = 0; it < 8; ++it) {
            int jBase = (it * 16 + wave) * 4;
            #pragma unroll
            for (int t = 0; t < 4; ++t) {
                int j = jBase + t;               // 0..511
                int node = p1l[j];
                float scl = t1l[j];
                const float2 v = *(const float2*)(xg + (size_t)node * DD + lane * 2);
                float pr  = waveReduceSum(v.x * wr0 + v.y * wr1);
                float po_ = waveReduceSum(v.x * wo0 + v.y * wo1);
                if (lane == 0) { srel2[j] = scl * pr; attn2[j] = scl * po_ + brel; }
            }
        }
    }
    __syncthreads();

    // ---- Phase 4: edge remap + layer-2 scatter ----
    #pragma unroll
    for (int it = 0; it < 4; ++it) {
        int eo = (it * 1024 + i) * 4;
        const int4 s4 = *(const int4*)(base + eo);
        const int4 d4 = *(const int4*)(base + NE + eo);
        int s2, d2;
        s2 = nidx[s4.x]; d2 = nidx[d4.x]; if ((s2 | d2) >= 0) atomicAdd(&attn2[d2], srel2[s2]);
        s2 = nidx[s4.y]; d2 = nidx[d4.y]; if ((s2 | d2) >= 0) atomicAdd(&attn2[d2], srel2[s2]);
        s2 = nidx[s4.z]; d2 = nidx[d4.z]; if ((s2 | d2) >= 0) atomicAdd(&attn2[d2], srel2[s2]);
        s2 = nidx[s4.w]; d2 = nidx[d4.w]; if ((s2 | d2) >= 0) atomicAdd(&attn2[d2], srel2[s2]);
    }
    __syncthreads();

    // ---- Phase 5: score + padded sort (512 real keys + 512 zero pads) ----
    {
        const float sgn = (w_sel[1] >= 0.f) ? 1.f : -1.f;
        unsigned long long key = (i < N1) ? make_key(attn2[i], sgn, i, N1) : 0ULL;
        key = bitonic_desc<N0>(key, keys, i);    // pads sink; 0..511 = desc real
        if (i < K2) {
            int idx = (N1 - 1) - (int)(key & 0xffffffffu);
            unsigned int ku = (unsigned int)(key >> 32);
            unsigned int fb = (ku & 0x80000000u) ? (ku ^ 0x80000000u) : ~ku;
            cn0[i] = p1l[idx];                        // composed node in x0
            cs[i]  = __uint_as_float(fb) * t1l[idx];  // composed scale
        }
    }
    __syncthreads();

    // ---- Phase 6: readout (R8's exact 4x64 partial tree, threads < 512) ----
    if (i < 512) {
        const int d = i & (DD - 1), q = i >> 7;      // q in 0..3, 64 rows each
        float sum = 0.f, mx = -3.0e38f;
        #pragma unroll 4
        for (int j = q * 64; j < q * 64 + 64; ++j) {
            float v = xg[(size_t)cn0[j] * DD + d] * cs[j];
            sum += v;
            mx = fmaxf(mx, v);
        }
        sm[q][d] = sum; mm[q][d] = mx;
    }
    __syncthreads();
    if (i < DD) {
        rr[i] = (sm[0][i] + sm[1][i] + sm[2][i] + sm[3][i]) * (1.f / 256.f);
    } else if (i < 2 * DD) {
        int dd = i - DD;
        rr[DD + dd] = fmaxf(fmaxf(mm[0][dd], mm[1][dd]), fmaxf(mm[2][dd], mm[3][dd]));
    }
    __syncthreads();
    if (i < 256) {
        int o = i & (NOUT - 1), c = i >> 6;          // c in 0..3
        float acc = 0.f;
        #pragma unroll
        for (int i2 = 0; i2 < 64; ++i2) {
            int ii = c * 64 + i2;
            acc += rr[ii] * W_lin[ii * NOUT + o];
        }
        po[c][o] = acc;
    }
    __syncthreads();
    if (i < NOUT)
        out[(size_t)g * NOUT + i] =
            b_lin[i] + po[0][i] + po[1][i] + po[2][i] + po[3][i];
}

// ---------------------------------------------------------------------------
extern "C" void kernel_launch(void* const* d_in, const int* in_sizes, int n_in,
                              void* d_out, int out_size, void* d_ws, size_t ws_size,
                              hipStream_t stream)
{
    const float* x0     = (const float*)d_in[0];  // (G, 1024, 128)
    const int*   ei     = (const int*)  d_in[1];  // (G, 2, E)
    const float* w_rel  = (const float*)d_in[2];  // (2, 128)
    const float* b_rel  = (const float*)d_in[3];  // (2,)
    const float* w_root = (const float*)d_in[4];  // (2, 128)
    const float* w_sel  = (const float*)d_in[5];  // (2,)
    const float* W_lin  = (const float*)d_in[6];  // (256, 64)
    const float* b_lin  = (const float*)d_in[7];  // (64,)
    float* out = (float*)d_out;
    (void)in_sizes; (void)n_in; (void)out_size; (void)d_ws; (void)ws_size;

    sag_all_kernel<<<NG, 1024, 0, stream>>>(
        x0, ei, w_rel, b_rel, w_root, w_sel, W_lin, b_lin, out);
}

// Round 11
// 167.190 us; speedup vs baseline: 1.2062x; 1.2062x over previous
//
#include <hip/hip_runtime.h>
#include <stdint.h>

#define NG   64      // graphs
#define N0   1024    // nodes layer 1
#define N1   512     // nodes layer 2 (k1)
#define K2   256     // k at layer 2
#define DD   128     // feature dim
#define NE   16384   // edges per graph
#define NOUT 64      // output dim

__device__ __forceinline__ float waveReduceSum(float v) {
    for (int off = 32; off > 0; off >>= 1) v += __shfl_xor(v, off, 64);
    return v;
}

// Hybrid bitonic sort, descending, 1 thread = 1 element.
// j<64 passes via shfl (no barriers), j>=64 via LDS (2 barriers each).
template<int NN>
__device__ __forceinline__ unsigned long long bitonic_desc(
    unsigned long long key, unsigned long long* lds, int i)
{
    for (int k2 = 2; k2 <= NN; k2 <<= 1) {
        for (int j = k2 >> 1; j > 0; j >>= 1) {
            unsigned long long p;
            if (j >= 64) {
                __syncthreads();
                lds[i] = key;
                __syncthreads();
                p = lds[i ^ j];
            } else {
                p = __shfl_xor(key, j, 64);
            }
            bool keepMax = (((i & k2) == 0) == ((i & j) == 0));
            if (keepMax ? (p > key) : (p < key)) key = p;
        }
    }
    return key;
}

// key = (monotone u32 of score) << 32 | (nn-1-i): descending sort gives
// score desc, index asc on ties — exact jax.lax.top_k semantics.
// All real keys map to u > 0, so 0-key pads sink below every real key.
__device__ __forceinline__ unsigned long long make_key(float attnv, float sgn, int i, int nn) {
    float sc = tanhf(attnv * sgn);
    unsigned int u = __float_as_uint(sc);
    u = (u & 0x80000000u) ? ~u : (u | 0x80000000u);
    return ((unsigned long long)u << 32) | (unsigned int)(nn - 1 - i);
}

// ---------------------------------------------------------------------------
// Kernel 1: ALL per-node dots in one 32 MB pass (row is in registers anyway).
// s_rel1 = x.w_rel1 ; attn1 = x.w_root1 + b0 ; s_rel2f = x.w_rel2 ;
// s_root2f = x.w_root2.  4096 blocks — full-device memory parallelism.
// ---------------------------------------------------------------------------
__global__ __launch_bounds__(256) void dots_all_kernel(
    const float* __restrict__ x,
    const float* __restrict__ w_rel, const float* __restrict__ w_root,
    const float* __restrict__ b_rel,
    float* __restrict__ s_rel1, float* __restrict__ attn1,
    float* __restrict__ s_rel2f, float* __restrict__ s_root2f,
    int totalNodes)
{
    int wave = blockIdx.x * 4 + (threadIdx.x >> 6);
    int lane = threadIdx.x & 63;
    float wr10 = w_rel[lane * 2],       wr11 = w_rel[lane * 2 + 1];
    float wo10 = w_root[lane * 2],      wo11 = w_root[lane * 2 + 1];
    float wr20 = w_rel[DD + lane * 2],  wr21 = w_rel[DD + lane * 2 + 1];
    float wo20 = w_root[DD + lane * 2], wo21 = w_root[DD + lane * 2 + 1];
    float b0 = b_rel[0];
    #pragma unroll
    for (int t = 0; t < 4; ++t) {
        int node = wave * 4 + t;
        if (node >= totalNodes) return;
        const float2 v = *(const float2*)(x + (size_t)node * DD + lane * 2);
        float p1 = waveReduceSum(v.x * wr10 + v.y * wr11);
        float p2 = waveReduceSum(v.x * wo10 + v.y * wo11);
        float p3 = waveReduceSum(v.x * wr20 + v.y * wr21);
        float p4 = waveReduceSum(v.x * wo20 + v.y * wo21);
        if (lane == 0) {
            s_rel1[node]   = p1;
            attn1[node]    = p2 + b0;
            s_rel2f[node]  = p3;
            s_root2f[node] = p4;
        }
    }
}

// ---------------------------------------------------------------------------
// Kernel 2: layer-1 per-graph: LDS scatter (deep-unrolled edge loads) + topk
// + layer-2 scalar prep (srel2/attn2 via scalar gathers — replaces gdots2).
// One block of 1024 threads per graph.
// ---------------------------------------------------------------------------
__global__ __launch_bounds__(1024) void graph1_kernel(
    const float* __restrict__ s_rel1,    // (G*N0)
    const float* __restrict__ attn1in,   // (G*N0) incl root+bias
    const float* __restrict__ s_rel2f,   // (G*N0)
    const float* __restrict__ s_root2f,  // (G*N0)
    const float* __restrict__ b_rel,     // (2,)
    const float* __restrict__ w_sel,     // (2,)
    const int*   __restrict__ ei,        // (G, 2, NE)
    int*   __restrict__ perm1,           // (G, N1)
    float* __restrict__ tops1,           // (G, N1)
    int*   __restrict__ newidx1,         // (G, N0)
    float* __restrict__ srel2out,        // (G, N1)
    float* __restrict__ attn2out)        // (G, N1)
{
    __shared__ float srel[N0];
    __shared__ float attn[N0];
    __shared__ unsigned long long keys[N0];
    const int g = blockIdx.x, i = threadIdx.x;

    srel[i] = s_rel1[(size_t)g * N0 + i];
    attn[i] = attn1in[(size_t)g * N0 + i];
    __syncthreads();

    // edge scatter: issue ALL loads first (8 int4 in flight), then atomics
    const int* base = ei + (size_t)g * 2 * NE;
    {
        int4 s4[4], d4[4];
        #pragma unroll
        for (int it = 0; it < 4; ++it) {
            int eo = (it * 1024 + i) * 4;
            s4[it] = *(const int4*)(base + eo);
            d4[it] = *(const int4*)(base + NE + eo);
        }
        #pragma unroll
        for (int it = 0; it < 4; ++it) {
            atomicAdd(&attn[d4[it].x], srel[s4[it].x]);
            atomicAdd(&attn[d4[it].y], srel[s4[it].y]);
            atomicAdd(&attn[d4[it].z], srel[s4[it].z]);
            atomicAdd(&attn[d4[it].w], srel[s4[it].w]);
        }
    }
    __syncthreads();

    const float sgn = (w_sel[0] >= 0.f) ? 1.f : -1.f;
    unsigned long long key = make_key(attn[i], sgn, i, N0);
    key = bitonic_desc<N0>(key, keys, i);

    int idx = (N0 - 1) - (int)(key & 0xffffffffu);
    unsigned int ku = (unsigned int)(key >> 32);
    unsigned int fb = (ku & 0x80000000u) ? (ku ^ 0x80000000u) : ~ku;
    newidx1[(size_t)g * N0 + idx] = (i < N1) ? i : -1;
    if (i < N1) {
        float t = __uint_as_float(fb);
        perm1[(size_t)g * N1 + i] = idx;
        tops1[(size_t)g * N1 + i] = t;
        // layer-2 dots via precomputed full-node scalars (bitwise == gdots2)
        srel2out[(size_t)g * N1 + i] = t * s_rel2f[(size_t)g * N0 + idx];
        attn2out[(size_t)g * N1 + i] = t * s_root2f[(size_t)g * N0 + idx] + b_rel[1];
    }
}

// ---------------------------------------------------------------------------
// Kernel 3: layer-2 per-graph: remap + LDS scatter + padded sort-1024 +
// fused readout + GEMV. One block of 1024 threads per graph.
// ---------------------------------------------------------------------------
__global__ __launch_bounds__(1024) void graph2_readout_kernel(
    const float* __restrict__ x0,        // (G, N0, D)
    const int*   __restrict__ ei,        // (G, 2, NE)
    const int*   __restrict__ newidx1,   // (G, N0)
    const int*   __restrict__ perm1,     // (G, N1)
    const float* __restrict__ tops1,     // (G, N1)
    const float* __restrict__ srel2in,   // (G, N1)
    const float* __restrict__ attn2in,   // (G, N1)
    const float* __restrict__ w_sel,     // (2,)
    const float* __restrict__ W_lin,     // (2D, OUT)
    const float* __restrict__ b_lin,     // (OUT)
    float* __restrict__ out)             // (G, OUT)
{
    __shared__ int   nidx[N0];
    __shared__ float srel[N1];
    __shared__ float attn[N1];
    __shared__ unsigned long long keys[N0];
    __shared__ int   p1l[N1];
    __shared__ float t1l[N1];
    __shared__ int   cn0[K2];
    __shared__ float cs[K2];
    __shared__ float sm[4][DD], mm[4][DD], rr[2 * DD], po[4][NOUT];

    const int g = blockIdx.x, i = threadIdx.x;
    const float* xg = x0 + (size_t)g * N0 * DD;
    nidx[i] = newidx1[(size_t)g * N0 + i];
    if (i < N1) {
        srel[i] = srel2in[(size_t)g * N1 + i];
        attn[i] = attn2in[(size_t)g * N1 + i];
        p1l[i]  = perm1[(size_t)g * N1 + i];
        t1l[i]  = tops1[(size_t)g * N1 + i];
    }
    __syncthreads();

    // remap + scatter: all edge loads in flight first, then atomics
    const int* base = ei + (size_t)g * 2 * NE;
    {
        int4 s4[4], d4[4];
        #pragma unroll
        for (int it = 0; it < 4; ++it) {
            int eo = (it * 1024 + i) * 4;
            s4[it] = *(const int4*)(base + eo);
            d4[it] = *(const int4*)(base + NE + eo);
        }
        #pragma unroll
        for (int it = 0; it < 4; ++it) {
            int s2, d2;
            s2 = nidx[s4[it].x]; d2 = nidx[d4[it].x]; if ((s2 | d2) >= 0) atomicAdd(&attn[d2], srel[s2]);
            s2 = nidx[s4[it].y]; d2 = nidx[d4[it].y]; if ((s2 | d2) >= 0) atomicAdd(&attn[d2], srel[s2]);
            s2 = nidx[s4[it].z]; d2 = nidx[d4[it].z]; if ((s2 | d2) >= 0) atomicAdd(&attn[d2], srel[s2]);
            s2 = nidx[s4[it].w]; d2 = nidx[d4[it].w]; if ((s2 | d2) >= 0) atomicAdd(&attn[d2], srel[s2]);
        }
    }
    __syncthreads();

    // padded sort: 512 real keys + 512 zero pads (pads sink; verified R9)
    {
        const float sgn = (w_sel[1] >= 0.f) ? 1.f : -1.f;
        unsigned long long key = (i < N1) ? make_key(attn[i], sgn, i, N1) : 0ULL;
        key = bitonic_desc<N0>(key, keys, i);
        if (i < K2) {
            int idx = (N1 - 1) - (int)(key & 0xffffffffu);
            unsigned int ku = (unsigned int)(key >> 32);
            unsigned int fb = (ku & 0x80000000u) ? (ku ^ 0x80000000u) : ~ku;
            cn0[i] = p1l[idx];                        // composed node in x0
            cs[i]  = __uint_as_float(fb) * t1l[idx];  // composed scale
        }
    }
    __syncthreads();

    // readout: mean/max over 256 rows of x0[cn0[j]] * cs[j] (R8/R9 tree)
    if (i < 512) {
        const int d = i & (DD - 1), q = i >> 7;      // q in 0..3, 64 rows each
        float sum = 0.f, mx = -3.0e38f;
        #pragma unroll 4
        for (int j = q * 64; j < q * 64 + 64; ++j) {
            float v = xg[(size_t)cn0[j] * DD + d] * cs[j];
            sum += v;
            mx = fmaxf(mx, v);
        }
        sm[q][d] = sum; mm[q][d] = mx;
    }
    __syncthreads();
    if (i < DD) {
        rr[i] = (sm[0][i] + sm[1][i] + sm[2][i] + sm[3][i]) * (1.f / 256.f);
    } else if (i < 2 * DD) {
        int dd = i - DD;
        rr[DD + dd] = fmaxf(fmaxf(mm[0][dd], mm[1][dd]), fmaxf(mm[2][dd], mm[3][dd]));
    }
    __syncthreads();
    if (i < 256) {
        int o = i & (NOUT - 1), c = i >> 6;          // c in 0..3
        float acc = 0.f;
        #pragma unroll
        for (int i2 = 0; i2 < 64; ++i2) {
            int ii = c * 64 + i2;
            acc += rr[ii] * W_lin[ii * NOUT + o];
        }
        po[c][o] = acc;
    }
    __syncthreads();
    if (i < NOUT)
        out[(size_t)g * NOUT + i] =
            b_lin[i] + po[0][i] + po[1][i] + po[2][i] + po[3][i];
}

// ---------------------------------------------------------------------------
extern "C" void kernel_launch(void* const* d_in, const int* in_sizes, int n_in,
                              void* d_out, int out_size, void* d_ws, size_t ws_size,
                              hipStream_t stream)
{
    const float* x0     = (const float*)d_in[0];  // (G, 1024, 128)
    const int*   ei     = (const int*)  d_in[1];  // (G, 2, E)
    const float* w_rel  = (const float*)d_in[2];  // (2, 128)
    const float* b_rel  = (const float*)d_in[3];  // (2,)
    const float* w_root = (const float*)d_in[4];  // (2, 128)
    const float* w_sel  = (const float*)d_in[5];  // (2,)
    const float* W_lin  = (const float*)d_in[6];  // (256, 64)
    const float* b_lin  = (const float*)d_in[7];  // (64,)
    float* out = (float*)d_out;
    (void)in_sizes; (void)n_in; (void)out_size; (void)ws_size;

    char* ws = (char*)d_ws;
    size_t off = 0;
    auto alloc = [&](size_t bytes) -> void* {
        off = (off + 255) & ~(size_t)255;
        void* p = ws + off;
        off += bytes;
        return p;
    };

    float* s_rel1   = (float*)alloc((size_t)NG * N0 * 4);
    float* attn1    = (float*)alloc((size_t)NG * N0 * 4);
    float* s_rel2f  = (float*)alloc((size_t)NG * N0 * 4);
    float* s_root2f = (float*)alloc((size_t)NG * N0 * 4);
    int*   perm1    = (int*)  alloc((size_t)NG * N1 * 4);
    float* tops1    = (float*)alloc((size_t)NG * N1 * 4);
    int*   newidx1  = (int*)  alloc((size_t)NG * N0 * 4);
    float* srel2    = (float*)alloc((size_t)NG * N1 * 4);
    float* attn2    = (float*)alloc((size_t)NG * N1 * 4);

    dots_all_kernel<<<(NG * N0) / 16, 256, 0, stream>>>(
        x0, w_rel, w_root, b_rel, s_rel1, attn1, s_rel2f, s_root2f, NG * N0);

    graph1_kernel<<<NG, 1024, 0, stream>>>(
        s_rel1, attn1, s_rel2f, s_root2f, b_rel, w_sel, ei,
        perm1, tops1, newidx1, srel2, attn2);

    graph2_readout_kernel<<<NG, 1024, 0, stream>>>(
        x0, ei, newidx1, perm1, tops1, srel2, attn2, w_sel + 0,
        W_lin, b_lin, out);
}

// Round 14
// 164.584 us; speedup vs baseline: 1.2252x; 1.0158x over previous
//
#include <hip/hip_runtime.h>
#include <stdint.h>

#define NG   64      // graphs
#define N0   1024    // nodes layer 1
#define N1   512     // nodes layer 2 (k1)
#define K2   256     // k at layer 2
#define DD   128     // feature dim
#define NE   16384   // edges per graph
#define NOUT 64      // output dim

__device__ __forceinline__ float waveReduceSum(float v) {
    for (int off = 32; off > 0; off >>= 1) v += __shfl_xor(v, off, 64);
    return v;
}

// Hybrid bitonic sort, descending, 1 thread = 1 element.
// j<64 passes via shfl (no barriers), j>=64 via LDS (2 barriers each).
template<int NN>
__device__ __forceinline__ unsigned long long bitonic_desc(
    unsigned long long key, unsigned long long* lds, int i)
{
    for (int k2 = 2; k2 <= NN; k2 <<= 1) {
        for (int j = k2 >> 1; j > 0; j >>= 1) {
            unsigned long long p;
            if (j >= 64) {
                __syncthreads();
                lds[i] = key;
                __syncthreads();
                p = lds[i ^ j];
            } else {
                p = __shfl_xor(key, j, 64);
            }
            bool keepMax = (((i & k2) == 0) == ((i & j) == 0));
            if (keepMax ? (p > key) : (p < key)) key = p;
        }
    }
    return key;
}

// key = (monotone u32 of score) << 32 | (nn-1-i): descending sort gives
// score desc, index asc on ties — exact jax.lax.top_k semantics.
// All real keys map to u > 0, so 0-key pads sink below every real key.
__device__ __forceinline__ unsigned long long make_key(float attnv, float sgn, int i, int nn) {
    float sc = tanhf(attnv * sgn);
    unsigned int u = __float_as_uint(sc);
    u = (u & 0x80000000u) ? ~u : (u | 0x80000000u);
    return ((unsigned long long)u << 32) | (unsigned int)(nn - 1 - i);
}

// ---------------------------------------------------------------------------
// Kernel 1: ALL per-node dots in one 32 MB pass. 4096 blocks (wide).
// s_rel1 = x.w_rel1 ; attn1 = x.w_root1 + b0 ; s_rel2f/s_root2f for layer 2.
// ---------------------------------------------------------------------------
__global__ __launch_bounds__(256) void dots_all_kernel(
    const float* __restrict__ x,
    const float* __restrict__ w_rel, const float* __restrict__ w_root,
    const float* __restrict__ b_rel,
    float* __restrict__ s_rel1, float* __restrict__ attn1,
    float* __restrict__ s_rel2f, float* __restrict__ s_root2f,
    int totalNodes)
{
    int wave = blockIdx.x * 4 + (threadIdx.x >> 6);
    int lane = threadIdx.x & 63;
    float wr10 = w_rel[lane * 2],       wr11 = w_rel[lane * 2 + 1];
    float wo10 = w_root[lane * 2],      wo11 = w_root[lane * 2 + 1];
    float wr20 = w_rel[DD + lane * 2],  wr21 = w_rel[DD + lane * 2 + 1];
    float wo20 = w_root[DD + lane * 2], wo21 = w_root[DD + lane * 2 + 1];
    float b0 = b_rel[0];
    #pragma unroll
    for (int t = 0; t < 4; ++t) {
        int node = wave * 4 + t;
        if (node >= totalNodes) return;
        const float2 v = *(const float2*)(x + (size_t)node * DD + lane * 2);
        float p1 = waveReduceSum(v.x * wr10 + v.y * wr11);
        float p2 = waveReduceSum(v.x * wo10 + v.y * wo11);
        float p3 = waveReduceSum(v.x * wr20 + v.y * wr21);
        float p4 = waveReduceSum(v.x * wo20 + v.y * wo21);
        if (lane == 0) {
            s_rel1[node]   = p1;
            attn1[node]    = p2 + b0;
            s_rel2f[node]  = p3;
            s_root2f[node] = p4;
        }
    }
}

// ---------------------------------------------------------------------------
// Kernel 2: per-graph EVERYTHING after the dots. One block (1024 thr) per
// graph. Edges loaded ONCE into registers, reused for both scatters.
// perm/tops/newidx/srel2/attn2 never touch global memory.
// ---------------------------------------------------------------------------
__global__ __launch_bounds__(1024) void graph_all_kernel(
    const float* __restrict__ x0,        // (G, N0, D)
    const int*   __restrict__ ei,        // (G, 2, NE)
    const float* __restrict__ s_rel1,    // (G*N0)
    const float* __restrict__ attn1in,   // (G*N0) incl root+bias
    const float* __restrict__ s_rel2f,   // (G*N0)
    const float* __restrict__ s_root2f,  // (G*N0)
    const float* __restrict__ b_rel,     // (2,)
    const float* __restrict__ w_sel,     // (2,)
    const float* __restrict__ W_lin,     // (2D, OUT)
    const float* __restrict__ b_lin,     // (OUT)
    float* __restrict__ out)             // (G, OUT)
{
    __shared__ float srel[N0];
    __shared__ float attn[N0];
    __shared__ unsigned long long keys[N0];
    __shared__ int   nidx[N0];
    __shared__ int   p1l[N1];
    __shared__ float t1l[N1];
    __shared__ float srel2[N1];
    __shared__ float attn2[N1];
    __shared__ int   cn0[K2];
    __shared__ float cs[K2];
    __shared__ float sm[4][DD], mm[4][DD], rr[2 * DD], po[4][NOUT];

    const int g = blockIdx.x, i = threadIdx.x;
    const float* xg = x0 + (size_t)g * N0 * DD;

    // prologue: scalars to LDS + edge list to registers (held through both
    // scatters — read from HBM exactly once)
    srel[i] = s_rel1[(size_t)g * N0 + i];
    attn[i] = attn1in[(size_t)g * N0 + i];
    int4 s4[4], d4[4];
    {
        const int* base = ei + (size_t)g * 2 * NE;
        #pragma unroll
        for (int it = 0; it < 4; ++it) {
            int eo = (it * 1024 + i) * 4;
            s4[it] = *(const int4*)(base + eo);
            d4[it] = *(const int4*)(base + NE + eo);
        }
    }
    __syncthreads();

    // ---- layer-1 scatter (LDS atomics) ----
    #pragma unroll
    for (int it = 0; it < 4; ++it) {
        atomicAdd(&attn[d4[it].x], srel[s4[it].x]);
        atomicAdd(&attn[d4[it].y], srel[s4[it].y]);
        atomicAdd(&attn[d4[it].z], srel[s4[it].z]);
        atomicAdd(&attn[d4[it].w], srel[s4[it].w]);
    }
    __syncthreads();

    // ---- layer-1 sort + select + layer-2 scalar prep ----
    {
        const float sgn = (w_sel[0] >= 0.f) ? 1.f : -1.f;
        const float b1 = b_rel[1];
        unsigned long long key = make_key(attn[i], sgn, i, N0);
        key = bitonic_desc<N0>(key, keys, i);
        int idx = (N0 - 1) - (int)(key & 0xffffffffu);
        unsigned int ku = (unsigned int)(key >> 32);
        unsigned int fb = (ku & 0x80000000u) ? (ku ^ 0x80000000u) : ~ku;
        nidx[idx] = (i < N1) ? i : -1;          // idx unique per thread
        if (i < N1) {
            float t = __uint_as_float(fb);
            p1l[i] = idx;
            t1l[i] = t;
            // layer-2 dots from precomputed full-node scalars (== gdots2)
            srel2[i] = t * s_rel2f[(size_t)g * N0 + idx];
            attn2[i] = t * s_root2f[(size_t)g * N0 + idx] + b1;
        }
    }
    __syncthreads();

    // ---- layer-2 remap + scatter (edges still in registers) ----
    #pragma unroll
    for (int it = 0; it < 4; ++it) {
        int s2, d2;
        s2 = nidx[s4[it].x]; d2 = nidx[d4[it].x]; if ((s2 | d2) >= 0) atomicAdd(&attn2[d2], srel2[s2]);
        s2 = nidx[s4[it].y]; d2 = nidx[d4[it].y]; if ((s2 | d2) >= 0) atomicAdd(&attn2[d2], srel2[s2]);
        s2 = nidx[s4[it].z]; d2 = nidx[d4[it].z]; if ((s2 | d2) >= 0) atomicAdd(&attn2[d2], srel2[s2]);
        s2 = nidx[s4[it].w]; d2 = nidx[d4[it].w]; if ((s2 | d2) >= 0) atomicAdd(&attn2[d2], srel2[s2]);
    }
    __syncthreads();

    // ---- layer-2 padded sort (512 real + 512 zero pads; verified R9) ----
    {
        const float sgn = (w_sel[1] >= 0.f) ? 1.f : -1.f;
        unsigned long long key = (i < N1) ? make_key(attn2[i], sgn, i, N1) : 0ULL;
        key = bitonic_desc<N0>(key, keys, i);
        if (i < K2) {
            int idx = (N1 - 1) - (int)(key & 0xffffffffu);
            unsigned int ku = (unsigned int)(key >> 32);
            unsigned int fb = (ku & 0x80000000u) ? (ku ^ 0x80000000u) : ~ku;
            cn0[i] = p1l[idx];                        // composed node in x0
            cs[i]  = __uint_as_float(fb) * t1l[idx];  // composed scale
        }
    }
    __syncthreads();

    // ---- readout: mean/max over 256 rows of x0[cn0[j]] * cs[j] ----
    if (i < 512) {
        const int d = i & (DD - 1), q = i >> 7;      // q in 0..3, 64 rows each
        float sum = 0.f, mx = -3.0e38f;
        #pragma unroll 4
        for (int j = q * 64; j < q * 64 + 64; ++j) {
            float v = xg[(size_t)cn0[j] * DD + d] * cs[j];
            sum += v;
            mx = fmaxf(mx, v);
        }
        sm[q][d] = sum; mm[q][d] = mx;
    }
    __syncthreads();
    if (i < DD) {
        rr[i] = (sm[0][i] + sm[1][i] + sm[2][i] + sm[3][i]) * (1.f / 256.f);
    } else if (i < 2 * DD) {
        int dd = i - DD;
        rr[DD + dd] = fmaxf(fmaxf(mm[0][dd], mm[1][dd]), fmaxf(mm[2][dd], mm[3][dd]));
    }
    __syncthreads();
    if (i < 256) {
        int o = i & (NOUT - 1), c = i >> 6;          // c in 0..3
        float acc = 0.f;
        #pragma unroll
        for (int i2 = 0; i2 < 64; ++i2) {
            int ii = c * 64 + i2;
            acc += rr[ii] * W_lin[ii * NOUT + o];
        }
        po[c][o] = acc;
    }
    __syncthreads();
    if (i < NOUT)
        out[(size_t)g * NOUT + i] =
            b_lin[i] + po[0][i] + po[1][i] + po[2][i] + po[3][i];
}

// ---------------------------------------------------------------------------
extern "C" void kernel_launch(void* const* d_in, const int* in_sizes, int n_in,
                              void* d_out, int out_size, void* d_ws, size_t ws_size,
                              hipStream_t stream)
{
    const float* x0     = (const float*)d_in[0];  // (G, 1024, 128)
    const int*   ei     = (const int*)  d_in[1];  // (G, 2, E)
    const float* w_rel  = (const float*)d_in[2];  // (2, 128)
    const float* b_rel  = (const float*)d_in[3];  // (2,)
    const float* w_root = (const float*)d_in[4];  // (2, 128)
    const float* w_sel  = (const float*)d_in[5];  // (2,)
    const float* W_lin  = (const float*)d_in[6];  // (256, 64)
    const float* b_lin  = (const float*)d_in[7];  // (64,)
    float* out = (float*)d_out;
    (void)in_sizes; (void)n_in; (void)out_size; (void)ws_size;

    char* ws = (char*)d_ws;
    size_t off = 0;
    auto alloc = [&](size_t bytes) -> void* {
        off = (off + 255) & ~(size_t)255;
        void* p = ws + off;
        off += bytes;
        return p;
    };

    float* s_rel1   = (float*)alloc((size_t)NG * N0 * 4);
    float* attn1    = (float*)alloc((size_t)NG * N0 * 4);
    float* s_rel2f  = (float*)alloc((size_t)NG * N0 * 4);
    float* s_root2f = (float*)alloc((size_t)NG * N0 * 4);

    dots_all_kernel<<<(NG * N0) / 16, 256, 0, stream>>>(
        x0, w_rel, w_root, b_rel, s_rel1, attn1, s_rel2f, s_root2f, NG * N0);

    graph_all_kernel<<<NG, 1024, 0, stream>>>(
        x0, ei, s_rel1, attn1, s_rel2f, s_root2f, b_rel, w_sel,
        W_lin, b_lin, out);
}